// Round 6
// baseline (482.421 us; speedup 1.0000x reference)
//
#include <hip/hip_runtime.h>
#include <math.h>

// Problem constants (setup_inputs: h,c,i,kk = 8,64,96,3; c2,n,d = 32,8,512)
#define H    8
#define N    8
#define D    512
#define C    64
#define C2   32
#define I    96        // spatial size (NOT the 3x3 kernel! kk=3)
#define II   9216      // 96*96

// d_out flat layout (return order T, M, P, w), f32:
// T (8,64,96,96)=4718592 | M (8,8,32,1,1)=2048 | P (8,8,64,96,96)=37748736 | w same
#define OFF_T 0
#define OFF_M 4718592
#define OFF_P 4720640
#define OFF_W 42469376

// ws layout (floats). Factored forms:
//   kp[n,h,d,a,b] = A_k[n,h,d] + B_k[h,b,d](px-part) + C_k[h,a,d](py-part)
//   s*24 - sb[e]  = F[n][ra*3+rb][h][e] + G2[ra][h][e][b] + H2[a][rb][h][e]
#define WS_AK 0         // [n][h][d]        4096
#define WS_AV 4096
#define WS_BK 8192      // [h][b][d]        49152
#define WS_BV 57344
#define WS_CK 106496    // [h][a][d]        49152
#define WS_CV 155648
#define WS_SS 204800    // [cls][e][d]      36864  (cls = ra*3+rb)
#define WS_SP 241664    // [ra][q][e][d]    36864
#define WS_SQ 278528    // [rb][p][e][d]    36864
#define WS_F  315392    // [n][cls][h][e]   36864
#define WS_G2 352256    // [ra][h][e][b]    147456
#define WS_H2 499712    // [a][rb][h][e]    147456
// total 647168 floats = 2.47 MiB

__device__ __forceinline__ int bcls(int x) { return x == 0 ? 0 : (x == I - 1 ? 2 : 1); }

// ---------------- K1: per-head Linear -> BN(train) -> ReLU -> M -------------
__global__ __launch_bounds__(256) void irf_embed(
    const float* __restrict__ X, const float* __restrict__ lin_w,
    const float* __restrict__ lin_b, const float* __restrict__ gamma,
    const float* __restrict__ beta, float* __restrict__ out)
{
    const int h = blockIdx.x, t = threadIdx.x;
    const int n = t >> 5, cc = t & 31;

    __shared__ float Xs[N * D];
    __shared__ float ys[N * C2];
    __shared__ float scale_s[C2], shift_s[C2];

    const float4* Xg  = (const float4*)(X + (size_t)h * N * D);
    float4*       Xs4 = (float4*)Xs;
    for (int idx = t; idx < N * D / 4; idx += 256) Xs4[idx] = Xg[idx];
    __syncthreads();

    const float4* wrow = (const float4*)(lin_w + ((size_t)h * C2 + cc) * D);
    const float4* xrow = (const float4*)(Xs + n * D);
    float a0 = 0.f, a1 = 0.f, a2 = 0.f, a3 = 0.f;
    #pragma unroll 4
    for (int k = 0; k < D / 4; ++k) {
        float4 xv = xrow[k], wv = wrow[k];
        a0 = fmaf(xv.x, wv.x, a0); a1 = fmaf(xv.y, wv.y, a1);
        a2 = fmaf(xv.z, wv.z, a2); a3 = fmaf(xv.w, wv.w, a3);
    }
    float y = (a0 + a1) + (a2 + a3) + lin_b[h * C2 + cc];
    ys[n * C2 + cc] = y;
    __syncthreads();

    if (t < C2) {  // biased var (jnp.var ddof=0), eps 1e-5
        float s = 0.f, ss = 0.f;
        #pragma unroll
        for (int j = 0; j < N; ++j) { float v = ys[j * C2 + t]; s += v; ss += v * v; }
        float mu  = s * (1.0f / N);
        float var = ss * (1.0f / N) - mu * mu;
        float sc  = rsqrtf(var + 1e-5f) * gamma[h * C2 + t];
        scale_s[t] = sc;
        shift_s[t] = beta[h * C2 + t] - mu * sc;
    }
    __syncthreads();

    float v = fmaxf(fmaf(y, scale_s[cc], shift_s[cc]), 0.0f);
    out[OFF_M + (n * H + h) * C2 + cc] = v;    // M (n,h,c2)
}

// ---------------- K2a: separable factors A/B/C + kernel col/row sums --------
__global__ __launch_bounds__(256) void irf_factors_a(
    const float* __restrict__ kw, const float* __restrict__ kb,
    const float* __restrict__ vw, const float* __restrict__ vb,
    const float* __restrict__ px, const float* __restrict__ py,
    const float* __restrict__ sw, const float* __restrict__ out,
    float* __restrict__ ws)
{
    int gid = blockIdx.x * 256 + threadIdx.x;   // 57344 total
    if (gid < 4096) {
        // A_k/A_v[n,h,d] = bias + sum_{c<32}(w[h,d,c]+w[h,d,32+c]) * M[n,h,c]
        int id = gid, d = id & 63, h = (id >> 6) & 7, n = id >> 9;
        const float* kwr = kw + ((size_t)h * C + d) * C;
        const float* vwr = vw + ((size_t)h * C + d) * C;
        const float* Mr  = out + OFF_M + (n * H + h) * C2;
        float ak = kb[h * C + d], av = vb[h * C + d];
        #pragma unroll 8
        for (int c = 0; c < C2; ++c) {
            float m = Mr[c];
            ak = fmaf(kwr[c] + kwr[C2 + c], m, ak);
            av = fmaf(vwr[c] + vwr[C2 + c], m, av);
        }
        ws[WS_AK + id] = ak;
        ws[WS_AV + id] = av;
    } else if (gid < 4096 + 49152) {
        // B_*[h,b,d] = sum_{c<32} w[h,d,c]*px[c,b]; C_*[h,a,d] with w[h,d,32+c]*py[c,a]
        int id = gid - 4096, d = id & 63, r = id >> 6, b = r % I, h = r / I;
        const float* kwr = kw + ((size_t)h * C + d) * C;
        const float* vwr = vw + ((size_t)h * C + d) * C;
        float bk = 0.f, bv = 0.f, ck = 0.f, cv = 0.f;
        #pragma unroll 8
        for (int c = 0; c < C2; ++c) {
            float pxv = px[c * I + b], pyv = py[c * I + b];
            bk = fmaf(kwr[c], pxv, bk);       bv = fmaf(vwr[c], pxv, bv);
            ck = fmaf(kwr[C2 + c], pyv, ck);  cv = fmaf(vwr[C2 + c], pyv, cv);
        }
        ws[WS_BK + id] = bk; ws[WS_BV + id] = bv;
        ws[WS_CK + id] = ck; ws[WS_CV + id] = cv;
    } else if (gid < 4096 + 49152 + 4096) {
        // per (e,d): SS[cls], SP[ra][q], SQ[rb][p] partial sums of sw[e,d,:,:]
        int id = gid - (4096 + 49152), d = id & 63, e = id >> 6;
        float k9[3][3];
        const float* swr = sw + (size_t)(e * C + d) * 9;
        #pragma unroll
        for (int p = 0; p < 3; ++p)
            #pragma unroll
            for (int q = 0; q < 3; ++q) k9[p][q] = swr[p * 3 + q];
        #pragma unroll
        for (int ra = 0; ra < 3; ++ra) {
            int pmin = (ra == 0) ? 1 : 0, pmax = (ra == 2) ? 1 : 2;
            #pragma unroll
            for (int q = 0; q < 3; ++q) {
                float sp = 0.f;
                for (int p = pmin; p <= pmax; ++p) sp += k9[p][q];
                ws[WS_SP + ((ra * 3 + q) * C + e) * C + d] = sp;
            }
            #pragma unroll
            for (int rb = 0; rb < 3; ++rb) {
                int qmin = (rb == 0) ? 1 : 0, qmax = (rb == 2) ? 1 : 2;
                float ssv = 0.f;
                for (int p = pmin; p <= pmax; ++p)
                    for (int q = qmin; q <= qmax; ++q) ssv += k9[p][q];
                ws[WS_SS + ((ra * 3 + rb) * C + e) * C + d] = ssv;
            }
        }
        #pragma unroll
        for (int rb = 0; rb < 3; ++rb) {
            int qmin = (rb == 0) ? 1 : 0, qmax = (rb == 2) ? 1 : 2;
            #pragma unroll
            for (int p = 0; p < 3; ++p) {
                float sq = 0.f;
                for (int q = qmin; q <= qmax; ++q) sq += k9[p][q];
                ws[WS_SQ + ((rb * 3 + p) * C + e) * C + d] = sq;
            }
        }
    }
}

// ---------------- K2b: conv precontractions F, G2, H2 -----------------------
__global__ __launch_bounds__(256) void irf_factors_b(float* __restrict__ ws)
{
    int gid = blockIdx.x * 256 + threadIdx.x;   // 331776 total
    if (gid < 36864) {
        // F[n][cls][h][e] = sum_d A_k[n,h,d] * SS[cls,e,d]
        int id = gid, e = id & 63, h = (id >> 6) & 7, cls = (id >> 9) % 9, n = id / 4608;
        const float* ak = ws + WS_AK + (n * H + h) * C;
        const float* ss = ws + WS_SS + (cls * C + e) * C;
        float acc = 0.f;
        #pragma unroll 8
        for (int d = 0; d < C; ++d) acc = fmaf(ak[d], ss[d], acc);
        ws[WS_F + id] = acc;
    } else if (gid < 36864 + 147456) {
        // G2[ra][h][e][b] = sum_{q in Q(cls(b))} sum_d SP[ra,q,e,d] * B_k[h,b+q-1,d]
        int j = gid - 36864, b = j % I, e = (j / I) & 63, h = (j / (I * C)) & 7, ra = j / (I * C * H);
        int rb = bcls(b), qmin = (rb == 0) ? 1 : 0, qmax = (rb == 2) ? 1 : 2;
        float acc = 0.f;
        for (int q = qmin; q <= qmax; ++q) {
            const float* sp = ws + WS_SP + ((ra * 3 + q) * C + e) * C;
            const float* bk = ws + WS_BK + ((h * I) + (b + q - 1)) * C;
            #pragma unroll 8
            for (int d = 0; d < C; ++d) acc = fmaf(sp[d], bk[d], acc);
        }
        ws[WS_G2 + j] = acc;
    } else if (gid < 36864 + 2 * 147456) {
        // H2[a][rb][h][e] = sum_{p in P(cls(a))} sum_d SQ[rb,p,e,d] * C_k[h,a+p-1,d]
        int j = gid - 36864 - 147456, e = j & 63, h = (j >> 6) & 7, rb = (j >> 9) % 3, a = j / 1536;
        int ra = bcls(a), pmin = (ra == 0) ? 1 : 0, pmax = (ra == 2) ? 1 : 2;
        float acc = 0.f;
        for (int p = pmin; p <= pmax; ++p) {
            const float* sq = ws + WS_SQ + ((rb * 3 + p) * C + e) * C;
            const float* ck = ws + WS_CK + ((h * I) + (a + p - 1)) * C;
            #pragma unroll 8
            for (int d = 0; d < C; ++d) acc = fmaf(sq[d], ck[d], acc);
        }
        ws[WS_H2 + j] = acc;
    }
}

// ---------------- K3: per-(n,a) site kernel: P, s->softmax->w, T ------------
__global__ __launch_bounds__(256) void irf_site(
    const float* __restrict__ px, const float* __restrict__ py,
    const float* __restrict__ sb, const float* __restrict__ ws,
    float* __restrict__ out)
{
    const int bid = blockIdx.x;          // 0..767 = n*96 + a
    const int n = bid / I, a = bid - n * I;
    const int ra = bcls(a);
    const int t = threadIdx.x;
    const int e8 = t >> 5, bl = t & 31;  // 8 e-groups x 32 b-lanes

    __shared__ float Fs[3 * 512];        // [rb][h][e]
    __shared__ float H2s[3 * 512];       // [rb][h][e]
    __shared__ float Avs[512];           // [h][e]
    __shared__ float Cvs[512];           // [h][e]  (C_v at this a)
    __shared__ float Ms_[256];           // [h][c2]
    __shared__ float pys[C2];
    __shared__ float sbs[C];

    {
        const float* fsrc = ws + WS_F + (n * 9 + ra * 3) * 512;   // 3 contiguous cls
        const float* hsrc = ws + WS_H2 + a * 1536;
        for (int o = t; o < 1536; o += 256) { Fs[o] = fsrc[o]; H2s[o] = hsrc[o]; }
        const float* avsrc = ws + WS_AV + n * 512;
        for (int o = t; o < 512; o += 256) {
            Avs[o] = avsrc[o];
            int h = o >> 6, e = o & 63;
            Cvs[o] = ws[WS_CV + ((h * I) + a) * C + e];
        }
        const float* msrc = out + OFF_M + n * 256;
        if (t < 256) Ms_[t] = msrc[t];
        if (t < C2)  pys[t] = py[t * I + a];
        if (t < C)   sbs[t] = sb[t];
    }
    __syncthreads();

    const float inv24 = 1.0f / 24.0f;    // 1/sqrt(c*kk*kk) = 1/sqrt(576)

    // s assembly + softmax over h + T
    for (int eb = 0; eb < 8; ++eb) {
        int e = eb * 8 + e8;
        float sbe = sbs[e];
        for (int bc = 0; bc < 3; ++bc) {
            int b = bc * 32 + bl;
            int rb = bcls(b);
            float sv[H];
            float mx = -1e30f;
            #pragma unroll
            for (int h = 0; h < H; ++h) {
                float s = Fs[rb * 512 + h * 64 + e] + H2s[rb * 512 + h * 64 + e]
                        + ws[WS_G2 + ((ra * H + h) * C + e) * I + b] + sbe;
                sv[h] = s * inv24;
                mx = fmaxf(mx, sv[h]);
            }
            float sum = 0.f;
            #pragma unroll
            for (int h = 0; h < H; ++h) { sv[h] = __expf(sv[h] - mx); sum += sv[h]; }
            float rs = 1.0f / sum;
            float T = 0.f;
            #pragma unroll
            for (int h = 0; h < H; ++h) {
                float w = sv[h] * rs;
                out[OFF_W + (size_t)(((n * H + h) * C + e) * I + a) * I + b] = w;
                float vp = Avs[h * 64 + e] + Cvs[h * 64 + e]
                         + ws[WS_BV + ((h * I) + b) * C + e];
                T = fmaf(w, vp, T);
            }
            out[OFF_T + (size_t)((n * C + e) * I + a) * I + b] = T;
        }
    }

    // P writes: P[n,h,c,a,b] = c<32 ? M[n,h,c]+px[c,b] : M[n,h,c-32]+py[c-32,a]
    for (int h = 0; h < H; ++h) {
        for (int cb = 0; cb < 8; ++cb) {
            int c = cb * 8 + e8;
            float base = (c < C2) ? Ms_[h * C2 + c] : (Ms_[h * C2 + c - C2] + pys[c - C2]);
            bool use_px = (c < C2);
            for (int bc = 0; bc < 3; ++bc) {
                int b = bc * 32 + bl;
                float val = use_px ? (base + px[c * I + b]) : base;
                out[OFF_P + (size_t)(((n * H + h) * C + c) * I + a) * I + b] = val;
            }
        }
    }
}

extern "C" void kernel_launch(void* const* d_in, const int* in_sizes, int n_in,
                              void* d_out, int out_size, void* d_ws, size_t ws_size,
                              hipStream_t stream) {
    // dict order, f32 (confirmed: in_sizes[1]==131072 branch, NaN probe ruled out bf16)
    const float* X     = (const float*)d_in[0];
    const float* lin_w = (const float*)d_in[1];
    const float* lin_b = (const float*)d_in[2];
    const float* gamma = (const float*)d_in[3];
    const float* beta  = (const float*)d_in[4];
    const float* px    = (const float*)d_in[5];
    const float* py    = (const float*)d_in[6];
    const float* kw    = (const float*)d_in[7];
    const float* kb    = (const float*)d_in[8];
    const float* vw    = (const float*)d_in[9];
    const float* vb    = (const float*)d_in[10];
    const float* sw    = (const float*)d_in[11];
    const float* sb    = (const float*)d_in[12];

    float* out = (float*)d_out;
    float* ws  = (float*)d_ws;     // needs 647168 floats = 2.47 MiB

    irf_embed    <<<8,    256, 0, stream>>>(X, lin_w, lin_b, gamma, beta, out);
    irf_factors_a<<<224,  256, 0, stream>>>(kw, kb, vw, vb, px, py, sw, out, ws);
    irf_factors_b<<<1296, 256, 0, stream>>>(ws);
    irf_site     <<<768,  256, 0, stream>>>(px, py, sb, ws, out);
}

// Round 7
// 413.542 us; speedup vs baseline: 1.1666x; 1.1666x over previous
//
#include <hip/hip_runtime.h>
#include <math.h>

// Problem constants (setup_inputs: h,c,i,kk = 8,64,96,3; c2,n,d = 32,8,512)
#define H    8
#define N    8
#define D    512
#define C    64
#define C2   32
#define I    96        // spatial size (kk=3 is the conv kernel)
#define II   9216      // 96*96

// d_out flat layout (return order T, M, P, w), f32:
// T (8,64,96,96)=4718592 | M (8,8,32,1,1)=2048 | P (8,8,64,96,96)=37748736 | w same
#define OFF_T 0
#define OFF_M 4718592
#define OFF_P 4720640
#define OFF_W 42469376

// ws layout (floats). Factored forms:
//   kp[n,h,d,a,b] = A_k[n,h,d] + B_k[h,b,d](px-part) + C_k[h,a,d](py-part)
//   s*24 - sb[e]  = F[n][ra*3+rb][h][e] + G2[ra][h][e][b] + H2[a][rb][h][e]
#define WS_AK 0         // [n][h][d]        4096
#define WS_AV 4096
#define WS_BK 8192      // [h][b][d]        49152   (d contiguous — for factors_b)
#define WS_BV 57344     // [h][e][b]        49152   (b contiguous — for site!)
#define WS_CK 106496    // [h][a][d]        49152
#define WS_CV 155648    // [h][a][d]
#define WS_SS 204800    // [cls][e][d]      36864  (cls = ra*3+rb)
#define WS_SP 241664    // [ra][q][e][d]    36864
#define WS_SQ 278528    // [rb][p][e][d]    36864
#define WS_F  315392    // [n][cls][h][e]   36864
#define WS_G2 352256    // [ra][h][e][b]    147456
#define WS_H2 499712    // [a][rb][h][e]    147456
// total 647168 floats = 2.47 MiB

__device__ __forceinline__ int bcls(int x) { return x == 0 ? 0 : (x == I - 1 ? 2 : 1); }

// ---------------- K1: per-head Linear -> BN(train) -> ReLU -> M -------------
__global__ __launch_bounds__(256) void irf_embed(
    const float* __restrict__ X, const float* __restrict__ lin_w,
    const float* __restrict__ lin_b, const float* __restrict__ gamma,
    const float* __restrict__ beta, float* __restrict__ out)
{
    const int h = blockIdx.x, t = threadIdx.x;
    const int n = t >> 5, cc = t & 31;

    __shared__ float Xs[N * D];
    __shared__ float ys[N * C2];
    __shared__ float scale_s[C2], shift_s[C2];

    const float4* Xg  = (const float4*)(X + (size_t)h * N * D);
    float4*       Xs4 = (float4*)Xs;
    for (int idx = t; idx < N * D / 4; idx += 256) Xs4[idx] = Xg[idx];
    __syncthreads();

    const float4* wrow = (const float4*)(lin_w + ((size_t)h * C2 + cc) * D);
    const float4* xrow = (const float4*)(Xs + n * D);
    float a0 = 0.f, a1 = 0.f, a2 = 0.f, a3 = 0.f;
    #pragma unroll 4
    for (int k = 0; k < D / 4; ++k) {
        float4 xv = xrow[k], wv = wrow[k];
        a0 = fmaf(xv.x, wv.x, a0); a1 = fmaf(xv.y, wv.y, a1);
        a2 = fmaf(xv.z, wv.z, a2); a3 = fmaf(xv.w, wv.w, a3);
    }
    float y = (a0 + a1) + (a2 + a3) + lin_b[h * C2 + cc];
    ys[n * C2 + cc] = y;
    __syncthreads();

    if (t < C2) {  // biased var (jnp.var ddof=0), eps 1e-5
        float s = 0.f, ss = 0.f;
        #pragma unroll
        for (int j = 0; j < N; ++j) { float v = ys[j * C2 + t]; s += v; ss += v * v; }
        float mu  = s * (1.0f / N);
        float var = ss * (1.0f / N) - mu * mu;
        float sc  = rsqrtf(var + 1e-5f) * gamma[h * C2 + t];
        scale_s[t] = sc;
        shift_s[t] = beta[h * C2 + t] - mu * sc;
    }
    __syncthreads();

    float v = fmaxf(fmaf(y, scale_s[cc], shift_s[cc]), 0.0f);
    out[OFF_M + (n * H + h) * C2 + cc] = v;    // M (n,h,c2)
}

// ---------------- K2a: separable factors A/B/C + kernel col/row sums --------
__global__ __launch_bounds__(256) void irf_factors_a(
    const float* __restrict__ kw, const float* __restrict__ kb,
    const float* __restrict__ vw, const float* __restrict__ vb,
    const float* __restrict__ px, const float* __restrict__ py,
    const float* __restrict__ sw, const float* __restrict__ out,
    float* __restrict__ ws)
{
    int gid = blockIdx.x * 256 + threadIdx.x;   // 57344 total
    if (gid < 4096) {
        // A_k/A_v[n,h,d] = bias + sum_{c<32}(w[h,d,c]+w[h,d,32+c]) * M[n,h,c]
        int id = gid, d = id & 63, h = (id >> 6) & 7, n = id >> 9;
        const float* kwr = kw + ((size_t)h * C + d) * C;
        const float* vwr = vw + ((size_t)h * C + d) * C;
        const float* Mr  = out + OFF_M + (n * H + h) * C2;
        float ak = kb[h * C + d], av = vb[h * C + d];
        #pragma unroll 8
        for (int c = 0; c < C2; ++c) {
            float m = Mr[c];
            ak = fmaf(kwr[c] + kwr[C2 + c], m, ak);
            av = fmaf(vwr[c] + vwr[C2 + c], m, av);
        }
        ws[WS_AK + id] = ak;
        ws[WS_AV + id] = av;
    } else if (gid < 4096 + 49152) {
        // B_*[h,b,d] = sum_{c<32} w[h,d,c]*px[c,b]; C_*[h,a,d] with w[h,d,32+c]*py[c,a]
        int id = gid - 4096, d = id & 63, r = id >> 6, b = r % I, h = r / I;
        const float* kwr = kw + ((size_t)h * C + d) * C;
        const float* vwr = vw + ((size_t)h * C + d) * C;
        float bk = 0.f, bv = 0.f, ck = 0.f, cv = 0.f;
        #pragma unroll 8
        for (int c = 0; c < C2; ++c) {
            float pxv = px[c * I + b], pyv = py[c * I + b];
            bk = fmaf(kwr[c], pxv, bk);       bv = fmaf(vwr[c], pxv, bv);
            ck = fmaf(kwr[C2 + c], pyv, ck);  cv = fmaf(vwr[C2 + c], pyv, cv);
        }
        ws[WS_BK + id] = bk;
        ws[WS_BV + (h * C + d) * I + b] = bv;   // TRANSPOSED: [h][e][b], b contig
        ws[WS_CK + id] = ck; ws[WS_CV + id] = cv;
    } else if (gid < 4096 + 49152 + 4096) {
        // per (e,d): SS[cls], SP[ra][q], SQ[rb][p] partial sums of sw[e,d,:,:]
        int id = gid - (4096 + 49152), d = id & 63, e = id >> 6;
        float k9[3][3];
        const float* swr = sw + (size_t)(e * C + d) * 9;
        #pragma unroll
        for (int p = 0; p < 3; ++p)
            #pragma unroll
            for (int q = 0; q < 3; ++q) k9[p][q] = swr[p * 3 + q];
        #pragma unroll
        for (int ra = 0; ra < 3; ++ra) {
            int pmin = (ra == 0) ? 1 : 0, pmax = (ra == 2) ? 1 : 2;
            #pragma unroll
            for (int q = 0; q < 3; ++q) {
                float sp = 0.f;
                for (int p = pmin; p <= pmax; ++p) sp += k9[p][q];
                ws[WS_SP + ((ra * 3 + q) * C + e) * C + d] = sp;
            }
            #pragma unroll
            for (int rb = 0; rb < 3; ++rb) {
                int qmin = (rb == 0) ? 1 : 0, qmax = (rb == 2) ? 1 : 2;
                float ssv = 0.f;
                for (int p = pmin; p <= pmax; ++p)
                    for (int q = qmin; q <= qmax; ++q) ssv += k9[p][q];
                ws[WS_SS + ((ra * 3 + rb) * C + e) * C + d] = ssv;
            }
        }
        #pragma unroll
        for (int rb = 0; rb < 3; ++rb) {
            int qmin = (rb == 0) ? 1 : 0, qmax = (rb == 2) ? 1 : 2;
            #pragma unroll
            for (int p = 0; p < 3; ++p) {
                float sq = 0.f;
                for (int q = qmin; q <= qmax; ++q) sq += k9[p][q];
                ws[WS_SQ + ((rb * 3 + p) * C + e) * C + d] = sq;
            }
        }
    }
}

// ---------------- K2b: conv precontractions F, G2, H2 -----------------------
__global__ __launch_bounds__(256) void irf_factors_b(float* __restrict__ ws)
{
    int gid = blockIdx.x * 256 + threadIdx.x;   // 331776 total
    if (gid < 36864) {
        // F[n][cls][h][e] = sum_d A_k[n,h,d] * SS[cls,e,d]
        int id = gid, e = id & 63, h = (id >> 6) & 7, cls = (id >> 9) % 9, n = id / 4608;
        const float* ak = ws + WS_AK + (n * H + h) * C;
        const float* ss = ws + WS_SS + (cls * C + e) * C;
        float acc = 0.f;
        #pragma unroll 8
        for (int d = 0; d < C; ++d) acc = fmaf(ak[d], ss[d], acc);
        ws[WS_F + id] = acc;
    } else if (gid < 36864 + 147456) {
        // G2[ra][h][e][b] = sum_{q in Q(cls(b))} sum_d SP[ra,q,e,d] * B_k[h,b+q-1,d]
        int j = gid - 36864, b = j % I, e = (j / I) & 63, h = (j / (I * C)) & 7, ra = j / (I * C * H);
        int rb = bcls(b), qmin = (rb == 0) ? 1 : 0, qmax = (rb == 2) ? 1 : 2;
        float acc = 0.f;
        for (int q = qmin; q <= qmax; ++q) {
            const float* sp = ws + WS_SP + ((ra * 3 + q) * C + e) * C;
            const float* bk = ws + WS_BK + ((h * I) + (b + q - 1)) * C;
            #pragma unroll 8
            for (int d = 0; d < C; ++d) acc = fmaf(sp[d], bk[d], acc);
        }
        ws[WS_G2 + j] = acc;
    } else if (gid < 36864 + 2 * 147456) {
        // H2[a][rb][h][e] = sum_{p in P(cls(a))} sum_d SQ[rb,p,e,d] * C_k[h,a+p-1,d]
        int j = gid - 36864 - 147456, e = j & 63, h = (j >> 6) & 7, rb = (j >> 9) % 3, a = j / 1536;
        int ra = bcls(a), pmin = (ra == 0) ? 1 : 0, pmax = (ra == 2) ? 1 : 2;
        float acc = 0.f;
        for (int p = pmin; p <= pmax; ++p) {
            const float* sq = ws + WS_SQ + ((rb * 3 + p) * C + e) * C;
            const float* ck = ws + WS_CK + ((h * I) + (a + p - 1)) * C;
            #pragma unroll 8
            for (int d = 0; d < C; ++d) acc = fmaf(sq[d], ck[d], acc);
        }
        ws[WS_H2 + j] = acc;
    }
}

// ---------------- K3: per-(n,a) site kernel, float4 over b ------------------
// s[h,e,b] = (FH[rb,h,e] + G2[ra,h,e,b]) / 24  with FH = F + H2 + sb
// vp[h,e,b] = AC[h,e] + BV[h,e,b]
__global__ __launch_bounds__(256) void irf_site(
    const float* __restrict__ px, const float* __restrict__ py,
    const float* __restrict__ sb, const float* __restrict__ ws,
    float* __restrict__ out)
{
    const int bid = blockIdx.x;          // 0..767 = n*96 + a
    const int n = bid / I, a = bid - n * I;
    const int ra = bcls(a);
    const int t = threadIdx.x;

    __shared__ float FH[3 * 512];        // [rb][h][e] = F + H2 + sb[e]
    __shared__ float AC[512];            // [h][e] = A_v + C_v(a)
    __shared__ float Ms_[256];           // [h][c2]
    __shared__ float pxs[C2 * I];        // [c][b]  12 KB
    __shared__ float pys[C2];

    {
        const float* fsrc = ws + WS_F + (n * 9 + ra * 3) * 512;   // 3 contiguous cls
        const float* hsrc = ws + WS_H2 + a * 1536;                // [rb][h][e] at this a
        for (int o = t; o < 1536; o += 256) FH[o] = fsrc[o] + hsrc[o] + sb[o & 63];
        const float* avsrc = ws + WS_AV + n * 512;
        for (int o = t; o < 512; o += 256) {
            int h = o >> 6, e = o & 63;
            AC[o] = avsrc[o] + ws[WS_CV + ((h * I) + a) * C + e];
        }
        Ms_[t] = out[OFF_M + n * 256 + t];
        for (int o = t; o < C2 * I; o += 256) pxs[o] = px[o];
        if (t < C2) pys[t] = py[t * I + a];
    }
    __syncthreads();

    const float inv24 = 1.0f / 24.0f;    // 1/sqrt(c*kk*kk) = 1/sqrt(576)

    // ---- softmax over h + w + T: 1536 items = (e, b4), float4 over b ----
    #pragma unroll
    for (int it = 0; it < 6; ++it) {
        int idx = it * 256 + t;
        int e = idx / 24, b4 = idx - e * 24;
        int b = b4 * 4;

        float4 sv[H];
        float4 mx = make_float4(-1e30f, -1e30f, -1e30f, -1e30f);
        #pragma unroll
        for (int h = 0; h < H; ++h) {
            float4 g2 = ((const float4*)(ws + WS_G2 + ((ra * H + h) * C + e) * I))[b4];
            float fh1 = FH[512 + h * 64 + e];            // rb=1 (interior)
            float fx = fh1, fw = fh1;
            if (b4 == 0)  fx = FH[h * 64 + e];           // b=0  -> rb=0
            if (b4 == 23) fw = FH[1024 + h * 64 + e];    // b=95 -> rb=2
            float4 s;
            s.x = (fx  + g2.x) * inv24;
            s.y = (fh1 + g2.y) * inv24;
            s.z = (fh1 + g2.z) * inv24;
            s.w = (fw  + g2.w) * inv24;
            sv[h] = s;
            mx.x = fmaxf(mx.x, s.x); mx.y = fmaxf(mx.y, s.y);
            mx.z = fmaxf(mx.z, s.z); mx.w = fmaxf(mx.w, s.w);
        }
        float4 sum = make_float4(0.f, 0.f, 0.f, 0.f);
        #pragma unroll
        for (int h = 0; h < H; ++h) {
            sv[h].x = __expf(sv[h].x - mx.x); sum.x += sv[h].x;
            sv[h].y = __expf(sv[h].y - mx.y); sum.y += sv[h].y;
            sv[h].z = __expf(sv[h].z - mx.z); sum.z += sv[h].z;
            sv[h].w = __expf(sv[h].w - mx.w); sum.w += sv[h].w;
        }
        float4 rs;
        rs.x = 1.0f / sum.x; rs.y = 1.0f / sum.y;
        rs.z = 1.0f / sum.z; rs.w = 1.0f / sum.w;

        float4 T = make_float4(0.f, 0.f, 0.f, 0.f);
        #pragma unroll
        for (int h = 0; h < H; ++h) {
            float4 w;
            w.x = sv[h].x * rs.x; w.y = sv[h].y * rs.y;
            w.z = sv[h].z * rs.z; w.w = sv[h].w * rs.w;
            ((float4*)(out + OFF_W + (size_t)(((n * H + h) * C + e) * I + a) * I))[b4] = w;
            float ac = AC[h * 64 + e];
            float4 bv = ((const float4*)(ws + WS_BV + (h * C + e) * I))[b4];
            T.x = fmaf(w.x, ac + bv.x, T.x);
            T.y = fmaf(w.y, ac + bv.y, T.y);
            T.z = fmaf(w.z, ac + bv.z, T.z);
            T.w = fmaf(w.w, ac + bv.w, T.w);
        }
        ((float4*)(out + OFF_T + (size_t)((n * C + e) * I + a) * I))[b4] = T;
    }

    // ---- P writes: 12288 items = (h, c, b4), float4 over b ----
    // P[n,h,c,a,b] = c<32 ? M[n,h,c]+px[c,b] : M[n,h,c-32]+py[c-32,a]
    #pragma unroll
    for (int it = 0; it < 48; ++it) {
        int idx = it * 256 + t;
        int b4 = idx % 24, rem = idx / 24;
        int c = rem & 63, h = rem >> 6;
        float4 v;
        if (c < C2) {
            float base = Ms_[h * C2 + c];
            float4 p4 = ((const float4*)(pxs + c * I))[b4];
            v.x = base + p4.x; v.y = base + p4.y;
            v.z = base + p4.z; v.w = base + p4.w;
        } else {
            float bb = Ms_[h * C2 + c - C2] + pys[c - C2];
            v = make_float4(bb, bb, bb, bb);
        }
        ((float4*)(out + OFF_P + (size_t)(((n * H + h) * C + c) * I + a) * I))[b4] = v;
    }
}

extern "C" void kernel_launch(void* const* d_in, const int* in_sizes, int n_in,
                              void* d_out, int out_size, void* d_ws, size_t ws_size,
                              hipStream_t stream) {
    // dict order, f32 (confirmed round 5/6)
    const float* X     = (const float*)d_in[0];
    const float* lin_w = (const float*)d_in[1];
    const float* lin_b = (const float*)d_in[2];
    const float* gamma = (const float*)d_in[3];
    const float* beta  = (const float*)d_in[4];
    const float* px    = (const float*)d_in[5];
    const float* py    = (const float*)d_in[6];
    const float* kw    = (const float*)d_in[7];
    const float* kb    = (const float*)d_in[8];
    const float* vw    = (const float*)d_in[9];
    const float* vb    = (const float*)d_in[10];
    const float* sw    = (const float*)d_in[11];
    const float* sb    = (const float*)d_in[12];

    float* out = (float*)d_out;
    float* ws  = (float*)d_ws;     // needs 647168 floats = 2.47 MiB

    irf_embed    <<<8,    256, 0, stream>>>(X, lin_w, lin_b, gamma, beta, out);
    irf_factors_a<<<224,  256, 0, stream>>>(kw, kb, vw, vb, px, py, sw, out, ws);
    irf_factors_b<<<1296, 256, 0, stream>>>(ws);
    irf_site     <<<768,  256, 0, stream>>>(px, py, sb, ws, out);
}